// Round 6
// baseline (694.763 us; speedup 1.0000x reference)
//
#include <hip/hip_runtime.h>
#include <hip/hip_bf16.h>
#include <stdint.h>

typedef unsigned short u16;
typedef unsigned int   u32;
typedef unsigned long long u64;
typedef __bf16 bf16x8 __attribute__((ext_vector_type(8)));
typedef float  f32x4  __attribute__((ext_vector_type(4)));
typedef short  s16x4  __attribute__((ext_vector_type(4)));

#define D_MODEL 1024
#define NH 16
#define DHEAD 64
#define BB 4
#define SS 2048
#define MM (BB*SS)   // 8192 rows

__device__ __forceinline__ u16 f2bf(float f) {
    unsigned int u = __float_as_uint(f);
    u += 0x7fffu + ((u >> 16) & 1u);   // RNE
    return (u16)(u >> 16);
}
__device__ __forceinline__ float bf2f(u16 s) {
    return __uint_as_float(((unsigned int)s) << 16);
}
__device__ __forceinline__ u32 pkbf(float a, float b) {  // v_cvt_pk_bf16_f32 (RNE)
    __hip_bfloat162 h = __float22bfloat162_rn(make_float2(a, b));
    return *(u32*)&h;
}

union U8 {
    uint4 q;
    u16   v[8];
    bf16x8 f;
};
union B8 { u32 w[4]; bf16x8 f; };
union V8 { s16x4 h[2]; bf16x8 f; };

// ---------------------------------------------------------------- merged cvt f32->bf16 (x, w_qkv, w_out)
#define N4X (MM * D_MODEL / 4)        // 2097152
#define N4W (D_MODEL * D_MODEL / 4)   // 262144
__global__ __launch_bounds__(256) void cvt_all_kernel(const float* __restrict__ x,
                                                      const float* __restrict__ wq,
                                                      const float* __restrict__ wo,
                                                      u16* __restrict__ xb,
                                                      u16* __restrict__ wqb,
                                                      u16* __restrict__ wob) {
    int i = blockIdx.x * 256 + threadIdx.x;
    const float* s; u16* d; int off;
    if (i < N4X)            { s = x;  d = xb;  off = i; }
    else if (i < N4X + N4W) { s = wq; d = wqb; off = i - N4X; }
    else                    { s = wo; d = wob; off = i - N4X - N4W; }
    float4 f = ((const float4*)s)[off];
    u32 o[2] = { pkbf(f.x, f.y), pkbf(f.z, f.w) };
    ((uint2*)d)[off] = *(const uint2*)o;
}

// ================================================================ GEMM core (BK=64, XOR-swizzled LDS)
template <bool PERMUTE_OUT>
__device__ __forceinline__ void gemm_body(const u16* __restrict__ A,
                                          const u16* __restrict__ Bt,
                                          const float* __restrict__ Bo,
                                          u16* __restrict__ Cq, u16* __restrict__ CqT,
                                          float* __restrict__ Out)
{
    __shared__ __align__(16) u16 As[128*64];
    __shared__ __align__(16) u16 Bs[128*64];

    const int tid  = threadIdx.x;
    const int wave = tid >> 6;
    const int lane = tid & 63;
    const int quad = lane >> 4;
    const int l16  = lane & 15;
    // XCD-chunked swizzle (bijective, grid 512 = 8 XCD * 64): blocks sharing bm co-locate on an XCD
    const int dsw = blockIdx.x;
    const int sl  = dsw >> 3;
    const int bm  = ((sl >> 3) << 3) + (dsw & 7);
    const int bn  = sl & 7;
    const int wm = wave >> 1, wn = wave & 1;

    f32x4 acc[4][4] = {};

    const int rp = tid >> 3;              // row in 32-row pass
    const int ch = tid & 7;               // physical chunk (8 elems)
    const int sc = ch ^ (rp & 7);         // source (logical) chunk

    const u16* Ab = A  + (size_t)(bm * 128 + rp) * D_MODEL + sc * 8;
    const u16* Bb = Bt + (size_t)(bn * 128 + rp) * D_MODEL + sc * 8;
    const int xr = l16 & 7;

    for (int k0 = 0; k0 < D_MODEL; k0 += 64) {
#pragma unroll
        for (int p = 0; p < 4; ++p) {
            __builtin_amdgcn_global_load_lds(
                (__attribute__((address_space(1))) void*)(Ab + (size_t)(32*p) * D_MODEL + k0),
                (__attribute__((address_space(3))) void*)(As + p*2048 + tid*8), 16, 0, 0);
            __builtin_amdgcn_global_load_lds(
                (__attribute__((address_space(1))) void*)(Bb + (size_t)(32*p) * D_MODEL + k0),
                (__attribute__((address_space(3))) void*)(Bs + p*2048 + tid*8), 16, 0, 0);
        }
        __syncthreads();

#pragma unroll
        for (int ks = 0; ks < 2; ++ks) {
            bf16x8 af[4], bfr[4];
#pragma unroll
            for (int t = 0; t < 4; ++t)
                af[t] = *(const bf16x8*)(const void*)(
                    As + (wm*64 + t*16 + l16)*64 + (((ks*4 + quad) ^ xr) * 8));
#pragma unroll
            for (int t = 0; t < 4; ++t)
                bfr[t] = *(const bf16x8*)(const void*)(
                    Bs + (wn*64 + t*16 + l16)*64 + (((ks*4 + quad) ^ xr) * 8));
#pragma unroll
            for (int i = 0; i < 4; ++i)
#pragma unroll
                for (int j = 0; j < 4; ++j)
                    acc[i][j] = __builtin_amdgcn_mfma_f32_16x16x32_bf16(af[i], bfr[j], acc[i][j], 0, 0, 0);
        }
        __syncthreads();
    }

    const int rowbase = bm*128 + wm*64;
    const int colbase = bn*128 + wn*64;
    if (PERMUTE_OUT) {
#pragma unroll
        for (int j = 0; j < 4; ++j) {
            const int col = colbase + j*16 + l16;
            const int h = col >> 6, dh = col & 63;
#pragma unroll
            for (int i = 0; i < 4; ++i) {
                const int row0 = rowbase + i*16 + quad*4;
                const int b = row0 >> 11, s0 = row0 & (SS - 1);
#pragma unroll
                for (int r = 0; r < 4; ++r)
                    Cq[(((size_t)(b*NH + h))*SS + s0 + r)*DHEAD + dh] = f2bf(acc[i][j][r]);
                u64 w = (u64)pkbf(acc[i][j][0], acc[i][j][1])
                      | ((u64)pkbf(acc[i][j][2], acc[i][j][3]) << 32);
                *(u64*)(CqT + ((size_t)((b*NH + h)*DHEAD + dh))*SS + s0) = w;
            }
        }
    } else {
#pragma unroll
        for (int j = 0; j < 4; ++j) {
            const int col = colbase + j*16 + l16;
            const float bias = Bo[col];
#pragma unroll
            for (int i = 0; i < 4; ++i) {
#pragma unroll
                for (int r = 0; r < 4; ++r) {
                    const int row = rowbase + i*16 + quad*4 + r;
                    Out[(size_t)row * D_MODEL + col] = acc[i][j][r] + bias;
                }
            }
        }
    }
}

__global__ __launch_bounds__(256) void gemm_qkv_kernel(const u16* __restrict__ A,
                                                       const u16* __restrict__ Bt,
                                                       u16* __restrict__ Cq,
                                                       u16* __restrict__ CqT) {
    gemm_body<true>(A, Bt, nullptr, Cq, CqT, nullptr);
}

__global__ __launch_bounds__(256) void gemm_out_kernel(const u16* __restrict__ A,
                                                       const u16* __restrict__ Bt,
                                                       const float* __restrict__ Bo,
                                                       float* __restrict__ Out) {
    gemm_body<false>(A, Bt, Bo, nullptr, nullptr, Out);
}

// ---------------------------------------------------------------- attention (Q=K=V), S^T formulation
// Intra-block key-split: 8 waves / 512 threads. Waves 0-3 (grp 0) process keys [0,1024),
// waves 4-7 (grp 1) keys [1024,2048) for the SAME 256 q -- doubles resident waves/CU (TLP)
// at identical HBM traffic. Each grp has its own double-buffered K/V LDS region; one shared
// barrier per iteration serves both. Partials merged through LDS at the end (exp2 with no
// max-tracking -> partial O and lsum combine exactly).
// Per-wave compute identical to r4 (proven): register-P full-rate PV, ones-MFMA lsum.
__global__ __launch_bounds__(512, 4) void attn_kernel(const u16* __restrict__ qkv,   // [B*H][2048][64]
                                                      const u16* __restrict__ qkvT,  // [B*H][64][2048]
                                                      u16* __restrict__ outb)        // [B][S][1024]
{
    __shared__ __align__(16) u16 smem[16384];   // 32 KB: Ks[2 grp][2 buf][2048] | Vt[2 grp][2 buf][2048]
    u16* Ks = smem;
    u16* Vt = smem + 8192;

    const int tid  = threadIdx.x;
    const int wave = tid >> 6;
    const int grp  = wave >> 2;      // key-split group
    const int w4   = wave & 3;
    const int lane = tid & 63;
    const int quad = lane >> 4;
    const int l16  = lane & 15;
    const int t    = tid & 255;      // within-group staging thread

    // XCD-chunked swizzle (bijective, grid 512 = 8 XCD * 64): 8 q-blocks of one bh share an XCD L2
    const int dsw  = blockIdx.x;
    const int sl   = dsw >> 3;
    const int bh   = ((sl >> 3) << 3) + (dsw & 7);
    const int qblk = sl & 7;
    const int b = bh >> 4, h = bh & 15;
    const int qbase = qblk * 256 + w4 * 64;

    const u16* Qp = qkv + (size_t)bh * SS * DHEAD;
    const float qscale = 0.125f * 1.4426950408889634f;  // 1/sqrt(64) * log2(e)

    // Q as B-operand frags (16x16x32): B[k=dh][n=q], lane reads 8 consecutive dh at fixed q
    bf16x8 qb[4][2];
#pragma unroll
    for (int nt = 0; nt < 4; ++nt)
#pragma unroll
        for (int ks = 0; ks < 2; ++ks) {
            U8 raw; raw.q = *(const uint4*)(Qp + (size_t)(qbase + nt*16 + l16)*DHEAD + ks*32 + quad*8);
            U8 w;
#pragma unroll
            for (int jj = 0; jj < 4; ++jj)
                ((u32*)&w)[jj] = pkbf(bf2f(raw.v[2*jj]) * qscale, bf2f(raw.v[2*jj+1]) * qscale);
            qb[nt][ks] = w.f;
        }

    // DMA staging sources (chunk-swizzled so frag reads are conflict-free); grp offset = 1024 keys
    const int rK = t >> 3, cK = (t & 7) ^ ((rK >> 1) & 7);
    const u16* srcK = qkv  + (size_t)bh * SS * DHEAD + (size_t)grp*1024*DHEAD + rK * DHEAD + cK * 8;
    const int rV = t >> 2, cV = (t & 3) ^ ((rV >> 1) & 3);
    const u16* srcV = qkvT + (size_t)bh * DHEAD * SS + (size_t)rV * SS + grp*1024 + cV * 8;

    u16* KsG = Ks + grp*4096;    // this group's [2 buf][2048]
    u16* VtG = Vt + grp*4096;

    // frag read offsets (r0-verified)
    const int h8 = (l16 >> 1) & 7, h4 = (l16 >> 1) & 3;
    const int ko0 = l16*64 + ((quad)     ^ h8) * 8;   // K frag, ks=0
    const int ko1 = l16*64 + ((4 + quad) ^ h8) * 8;   // K frag, ks=1
    const int vo0 = l16*32 + (((quad >> 1))     ^ h4) * 8 + (quad & 1) * 4;   // V keys 4q..4q+3
    const int vo1 = l16*32 + ((2 + (quad >> 1)) ^ h4) * 8 + (quad & 1) * 4;   // V keys 16+4q..+3

    bf16x8 ones;
#pragma unroll
    for (int j = 0; j < 8; ++j) ones[j] = (__bf16)1.0f;

    f32x4 ot[4][4] = {};    // O^T[dh-tile][q-tile] partial over this grp's keys
    f32x4 lsum[4]  = {};

    // prime buffer 0
    __builtin_amdgcn_global_load_lds(
        (__attribute__((address_space(1))) void*)(srcK),
        (__attribute__((address_space(3))) void*)(KsG + t*8), 16, 0, 0);
    __builtin_amdgcn_global_load_lds(
        (__attribute__((address_space(1))) void*)(srcV),
        (__attribute__((address_space(3))) void*)(VtG + t*8), 16, 0, 0);

#pragma unroll 2
    for (int kt = 0; kt < SS/64; ++kt) {      // 32 iterations: each grp covers 1024 keys
        __syncthreads();   // drains DMA for tile kt (both groups)
        if (kt < SS/64 - 1) {   // prefetch kt+1 into other buffer (in flight during compute)
            __builtin_amdgcn_global_load_lds(
                (__attribute__((address_space(1))) void*)(srcK + (size_t)(kt+1)*32*DHEAD),
                (__attribute__((address_space(3))) void*)(KsG + ((kt+1)&1)*2048 + t*8), 16, 0, 0);
            __builtin_amdgcn_global_load_lds(
                (__attribute__((address_space(1))) void*)(srcV + (kt+1)*32),
                (__attribute__((address_space(3))) void*)(VtG + ((kt+1)&1)*2048 + t*8), 16, 0, 0);
        }
        const u16* Kb = KsG + (kt&1)*2048;
        const u16* Vb = VtG + (kt&1)*2048;

        // V^T frags hoisted early (independent of S; LDS latency hides under QK MFMAs)
        V8 vt[4];
#pragma unroll
        for (int dt = 0; dt < 4; ++dt) {
            vt[dt].h[0] = *(const s16x4*)(const void*)(Vb + dt*512 + vo0);
            vt[dt].h[1] = *(const s16x4*)(const void*)(Vb + dt*512 + vo1);
        }

        // S^T = K * Q^T, sequential over mt to cap live f32 registers
        B8 pb[4];
#pragma unroll
        for (int mt = 0; mt < 2; ++mt) {
            bf16x8 kf0 = *(const bf16x8*)(const void*)(Kb + mt*1024 + ko0);
            bf16x8 kf1 = *(const bf16x8*)(const void*)(Kb + mt*1024 + ko1);
            f32x4 s[4] = {};
            __builtin_amdgcn_s_setprio(1);
#pragma unroll
            for (int nt = 0; nt < 4; ++nt)
                s[nt] = __builtin_amdgcn_mfma_f32_16x16x32_bf16(kf0, qb[nt][0], s[nt], 0, 0, 0);
#pragma unroll
            for (int nt = 0; nt < 4; ++nt)
                s[nt] = __builtin_amdgcn_mfma_f32_16x16x32_bf16(kf1, qb[nt][1], s[nt], 0, 0, 0);
            __builtin_amdgcn_s_setprio(0);
#pragma unroll
            for (int nt = 0; nt < 4; ++nt) {
                float p0 = __builtin_amdgcn_exp2f(s[nt][0]);
                float p1 = __builtin_amdgcn_exp2f(s[nt][1]);
                float p2 = __builtin_amdgcn_exp2f(s[nt][2]);
                float p3 = __builtin_amdgcn_exp2f(s[nt][3]);
                pb[nt].w[2*mt]   = pkbf(p0, p1);
                pb[nt].w[2*mt+1] = pkbf(p2, p3);
            }
        }

        // lsum += ones * P (full 32-key sum, permutation-invariant, every lane gets the total)
        // O^T  += V^T * P^T (full-rate 16x16x32; operands share the slot->key permutation)
        __builtin_amdgcn_s_setprio(1);
#pragma unroll
        for (int nt = 0; nt < 4; ++nt)
            lsum[nt] = __builtin_amdgcn_mfma_f32_16x16x32_bf16(ones, pb[nt].f, lsum[nt], 0, 0, 0);
#pragma unroll
        for (int dt = 0; dt < 4; ++dt)
#pragma unroll
            for (int nt = 0; nt < 4; ++nt)
                ot[dt][nt] = __builtin_amdgcn_mfma_f32_16x16x32_bf16(vt[dt].f, pb[nt].f, ot[dt][nt], 0, 0, 0);
        __builtin_amdgcn_s_setprio(0);
    }

    // ---------------- merge grp 0 partials into grp 1 through LDS ----------------
    __syncthreads();    // all compute done; smem free for reuse
    float* ex = (float*)smem;   // 32 KB = 8192 floats; per chunk use 256 slots * 16 f32 = 16 KB

    // lsum merge
    if (grp == 0) {
#pragma unroll
        for (int nt = 0; nt < 4; ++nt) ex[(w4*64 + lane)*4 + nt] = lsum[nt][0];
    }
    __syncthreads();
    float inv[4];
    if (grp == 1) {
#pragma unroll
        for (int nt = 0; nt < 4; ++nt)
            inv[nt] = 1.0f / (lsum[nt][0] + ex[(w4*64 + lane)*4 + nt]);
    }
    __syncthreads();

    // O merge, chunked by dt
#pragma unroll
    for (int dt = 0; dt < 4; ++dt) {
        if (grp == 0) {
            f32x4* dst = (f32x4*)ex + (w4*64 + lane)*4;
#pragma unroll
            for (int nt = 0; nt < 4; ++nt) dst[nt] = ot[dt][nt];
        }
        __syncthreads();
        if (grp == 1) {
            const f32x4* src = (const f32x4*)ex + (w4*64 + lane)*4;
#pragma unroll
            for (int nt = 0; nt < 4; ++nt) ot[dt][nt] += src[nt];
        }
        __syncthreads();
    }

    // epilogue (grp 1 only): O = O^T / lsum, packed 8B stores (4 consecutive dh per lane)
    if (grp == 1) {
#pragma unroll
        for (int dt = 0; dt < 4; ++dt)
#pragma unroll
            for (int nt = 0; nt < 4; ++nt) {
                u64 w = (u64)pkbf(ot[dt][nt][0]*inv[nt], ot[dt][nt][1]*inv[nt])
                      | ((u64)pkbf(ot[dt][nt][2]*inv[nt], ot[dt][nt][3]*inv[nt]) << 32);
                *(u64*)(outb + ((size_t)(b*SS + qbase + nt*16 + l16))*D_MODEL
                             + h*64 + dt*16 + quad*4) = w;
            }
    }
}

// ---------------------------------------------------------------- launcher
extern "C" void kernel_launch(void* const* d_in, const int* in_sizes, int n_in,
                              void* d_out, int out_size, void* d_ws, size_t ws_size,
                              hipStream_t stream)
{
    (void)in_sizes; (void)n_in; (void)out_size; (void)ws_size;
    const float* x  = (const float*)d_in[0];
    const float* wq = (const float*)d_in[1];
    const float* wo = (const float*)d_in[2];
    const float* bo = (const float*)d_in[3];

    char* ws = (char*)d_ws;
    u16* xb    = (u16*)(ws);                          // 16 MiB  [8192][1024] bf16 x
    u16* wqb   = (u16*)(ws + (size_t)(16 << 20));     //  2 MiB
    u16* wob   = (u16*)(ws + (size_t)(18 << 20));     //  2 MiB
    u16* qkvb  = (u16*)(ws + (size_t)(20 << 20));     // 16 MiB  [64][2048][64]
    u16* qkvTb = (u16*)(ws + (size_t)(36 << 20));     // 16 MiB  [64][64][2048]
    u16* attb  = xb;                                  // reuse x-bf16 buffer for attention output

    cvt_all_kernel<<<(N4X + 2*N4W) / 256, 256, 0, stream>>>(x, wq, wo, xb, wqb, wob);
    gemm_qkv_kernel<<<(MM/128) * (D_MODEL/128), 256, 0, stream>>>(xb, wqb, qkvb, qkvTb);
    attn_kernel<<<BB * NH * (SS/256), 512, 0, stream>>>(qkvb, qkvTb, attb);
    gemm_out_kernel<<<(MM/128) * (D_MODEL/128), 256, 0, stream>>>(attb, wob, bo, (float*)d_out);
}

// Round 7
// 218.842 us; speedup vs baseline: 3.1747x; 3.1747x over previous
//
#include <hip/hip_runtime.h>
#include <hip/hip_bf16.h>
#include <stdint.h>

typedef unsigned short u16;
typedef unsigned int   u32;
typedef unsigned long long u64;
typedef __bf16 bf16x8 __attribute__((ext_vector_type(8)));
typedef float  f32x4  __attribute__((ext_vector_type(4)));
typedef short  s16x4  __attribute__((ext_vector_type(4)));

#define D_MODEL 1024
#define NH 16
#define DHEAD 64
#define BB 4
#define SS 2048
#define MM (BB*SS)   // 8192 rows

__device__ __forceinline__ u16 f2bf(float f) {
    unsigned int u = __float_as_uint(f);
    u += 0x7fffu + ((u >> 16) & 1u);   // RNE
    return (u16)(u >> 16);
}
__device__ __forceinline__ float bf2f(u16 s) {
    return __uint_as_float(((unsigned int)s) << 16);
}
__device__ __forceinline__ u32 pkbf(float a, float b) {  // v_cvt_pk_bf16_f32 (RNE)
    __hip_bfloat162 h = __float22bfloat162_rn(make_float2(a, b));
    return *(u32*)&h;
}

union U8 {
    uint4 q;
    u16   v[8];
    bf16x8 f;
};
union B8 { u32 w[4]; bf16x8 f; };
union V8 { s16x4 h[2]; bf16x8 f; };

// ---------------------------------------------------------------- merged cvt f32->bf16 (x, w_qkv, w_out)
#define N4X (MM * D_MODEL / 4)        // 2097152
#define N4W (D_MODEL * D_MODEL / 4)   // 262144
__global__ __launch_bounds__(256) void cvt_all_kernel(const float* __restrict__ x,
                                                      const float* __restrict__ wq,
                                                      const float* __restrict__ wo,
                                                      u16* __restrict__ xb,
                                                      u16* __restrict__ wqb,
                                                      u16* __restrict__ wob) {
    int i = blockIdx.x * 256 + threadIdx.x;
    const float* s; u16* d; int off;
    if (i < N4X)            { s = x;  d = xb;  off = i; }
    else if (i < N4X + N4W) { s = wq; d = wqb; off = i - N4X; }
    else                    { s = wo; d = wob; off = i - N4X - N4W; }
    float4 f = ((const float4*)s)[off];
    u32 o[2] = { pkbf(f.x, f.y), pkbf(f.z, f.w) };
    ((uint2*)d)[off] = *(const uint2*)o;
}

// ================================================================ GEMM core (BK=64, XOR-swizzled LDS)
template <bool PERMUTE_OUT>
__device__ __forceinline__ void gemm_body(const u16* __restrict__ A,
                                          const u16* __restrict__ Bt,
                                          const float* __restrict__ Bo,
                                          u16* __restrict__ Cq, u16* __restrict__ CqT,
                                          float* __restrict__ Out)
{
    __shared__ __align__(16) u16 As[128*64];
    __shared__ __align__(16) u16 Bs[128*64];

    const int tid  = threadIdx.x;
    const int wave = tid >> 6;
    const int lane = tid & 63;
    const int quad = lane >> 4;
    const int l16  = lane & 15;
    // XCD-chunked swizzle (bijective, grid 512 = 8 XCD * 64): blocks sharing bm co-locate on an XCD
    const int dsw = blockIdx.x;
    const int sl  = dsw >> 3;
    const int bm  = ((sl >> 3) << 3) + (dsw & 7);
    const int bn  = sl & 7;
    const int wm = wave >> 1, wn = wave & 1;

    f32x4 acc[4][4] = {};

    const int rp = tid >> 3;              // row in 32-row pass
    const int ch = tid & 7;               // physical chunk (8 elems)
    const int sc = ch ^ (rp & 7);         // source (logical) chunk

    const u16* Ab = A  + (size_t)(bm * 128 + rp) * D_MODEL + sc * 8;
    const u16* Bb = Bt + (size_t)(bn * 128 + rp) * D_MODEL + sc * 8;
    const int xr = l16 & 7;

    for (int k0 = 0; k0 < D_MODEL; k0 += 64) {
#pragma unroll
        for (int p = 0; p < 4; ++p) {
            __builtin_amdgcn_global_load_lds(
                (__attribute__((address_space(1))) void*)(Ab + (size_t)(32*p) * D_MODEL + k0),
                (__attribute__((address_space(3))) void*)(As + p*2048 + tid*8), 16, 0, 0);
            __builtin_amdgcn_global_load_lds(
                (__attribute__((address_space(1))) void*)(Bb + (size_t)(32*p) * D_MODEL + k0),
                (__attribute__((address_space(3))) void*)(Bs + p*2048 + tid*8), 16, 0, 0);
        }
        __syncthreads();

#pragma unroll
        for (int ks = 0; ks < 2; ++ks) {
            bf16x8 af[4], bfr[4];
#pragma unroll
            for (int t = 0; t < 4; ++t)
                af[t] = *(const bf16x8*)(const void*)(
                    As + (wm*64 + t*16 + l16)*64 + (((ks*4 + quad) ^ xr) * 8));
#pragma unroll
            for (int t = 0; t < 4; ++t)
                bfr[t] = *(const bf16x8*)(const void*)(
                    Bs + (wn*64 + t*16 + l16)*64 + (((ks*4 + quad) ^ xr) * 8));
#pragma unroll
            for (int i = 0; i < 4; ++i)
#pragma unroll
                for (int j = 0; j < 4; ++j)
                    acc[i][j] = __builtin_amdgcn_mfma_f32_16x16x32_bf16(af[i], bfr[j], acc[i][j], 0, 0, 0);
        }
        __syncthreads();
    }

    const int rowbase = bm*128 + wm*64;
    const int colbase = bn*128 + wn*64;
    if (PERMUTE_OUT) {
#pragma unroll
        for (int j = 0; j < 4; ++j) {
            const int col = colbase + j*16 + l16;
            const int h = col >> 6, dh = col & 63;
#pragma unroll
            for (int i = 0; i < 4; ++i) {
                const int row0 = rowbase + i*16 + quad*4;
                const int b = row0 >> 11, s0 = row0 & (SS - 1);
#pragma unroll
                for (int r = 0; r < 4; ++r)
                    Cq[(((size_t)(b*NH + h))*SS + s0 + r)*DHEAD + dh] = f2bf(acc[i][j][r]);
                u64 w = (u64)pkbf(acc[i][j][0], acc[i][j][1])
                      | ((u64)pkbf(acc[i][j][2], acc[i][j][3]) << 32);
                *(u64*)(CqT + ((size_t)((b*NH + h)*DHEAD + dh))*SS + s0) = w;
            }
        }
    } else {
#pragma unroll
        for (int j = 0; j < 4; ++j) {
            const int col = colbase + j*16 + l16;
            const float bias = Bo[col];
#pragma unroll
            for (int i = 0; i < 4; ++i) {
#pragma unroll
                for (int r = 0; r < 4; ++r) {
                    const int row = rowbase + i*16 + quad*4 + r;
                    Out[(size_t)row * D_MODEL + col] = acc[i][j][r] + bias;
                }
            }
        }
    }
}

__global__ __launch_bounds__(256) void gemm_qkv_kernel(const u16* __restrict__ A,
                                                       const u16* __restrict__ Bt,
                                                       u16* __restrict__ Cq,
                                                       u16* __restrict__ CqT) {
    gemm_body<true>(A, Bt, nullptr, Cq, CqT, nullptr);
}

__global__ __launch_bounds__(256) void gemm_out_kernel(const u16* __restrict__ A,
                                                       const u16* __restrict__ Bt,
                                                       const float* __restrict__ Bo,
                                                       float* __restrict__ Out) {
    gemm_body<false>(A, Bt, Bo, nullptr, nullptr, Out);
}

// ---------------------------------------------------------------- attention (Q=K=V), S^T formulation
// r4 compute (proven: register-P full-rate PV, ones-MFMA lsum, 64 q/wave) with the depth-1
// __syncthreads pipeline replaced by TRIPLE-buffered K/V + counted vmcnt + raw s_barrier:
//   * tiles issued 2 iterations ahead -> DMA has ~2 iterations to land
//   * per-kt sync = single asm "s_waitcnt vmcnt(2); s_barrier" (memory clobber), never vmcnt(0)
//     in steady state -> the barrier stops draining the in-flight prefetches (T3/T4).
// Buffer-reuse safety: tile kt+2 writes buf[(kt+2)%3], which was last READ at kt-1 and fully
// consumed (register use) before the kt barrier all waves passed. Last 2 iterations peeled
// (vmcnt(2) -> vmcnt(0)).
__global__ __launch_bounds__(256, 2) void attn_kernel(const u16* __restrict__ qkv,   // [B*H][2048][64]
                                                      const u16* __restrict__ qkvT,  // [B*H][64][2048]
                                                      u16* __restrict__ outb)        // [B][S][1024]
{
    __shared__ __align__(16) u16 Ks[3*2048];    // 3 buf x [32 key][64 dh] chunk-swizzled
    __shared__ __align__(16) u16 Vt[3*2048];    // 3 buf x [64 dh][32 key] chunk-swizzled

    const int tid  = threadIdx.x;
    const int wave = tid >> 6;
    const int lane = tid & 63;
    const int quad = lane >> 4;
    const int l16  = lane & 15;

    // XCD-chunked swizzle (bijective, grid 512 = 8 XCD * 64): 8 q-blocks of one bh share an XCD L2
    const int dsw  = blockIdx.x;
    const int sl   = dsw >> 3;
    const int bh   = ((sl >> 3) << 3) + (dsw & 7);
    const int qblk = sl & 7;
    const int b = bh >> 4, h = bh & 15;
    const int qbase = qblk * 256 + wave * 64;

    const u16* Qp = qkv + (size_t)bh * SS * DHEAD;
    const float qscale = 0.125f * 1.4426950408889634f;  // 1/sqrt(64) * log2(e)

    // Q as B-operand frags (16x16x32): B[k=dh][n=q], lane reads 8 consecutive dh at fixed q
    bf16x8 qb[4][2];
#pragma unroll
    for (int nt = 0; nt < 4; ++nt)
#pragma unroll
        for (int ks = 0; ks < 2; ++ks) {
            U8 raw; raw.q = *(const uint4*)(Qp + (size_t)(qbase + nt*16 + l16)*DHEAD + ks*32 + quad*8);
            U8 w;
#pragma unroll
            for (int jj = 0; jj < 4; ++jj)
                ((u32*)&w)[jj] = pkbf(bf2f(raw.v[2*jj]) * qscale, bf2f(raw.v[2*jj+1]) * qscale);
            qb[nt][ks] = w.f;
        }

    // DMA staging sources (chunk-swizzled so frag reads are conflict-free)
    const int rK = tid >> 3, cK = (tid & 7) ^ ((rK >> 1) & 7);
    const u16* srcK = qkv  + (size_t)bh * SS * DHEAD + rK * DHEAD + cK * 8;
    const int rV = tid >> 2, cV = (tid & 3) ^ ((rV >> 1) & 3);
    const u16* srcV = qkvT + (size_t)bh * DHEAD * SS + (size_t)rV * SS + cV * 8;

    // frag read offsets (r0-verified)
    const int h8 = (l16 >> 1) & 7, h4 = (l16 >> 1) & 3;
    const int ko0 = l16*64 + ((quad)     ^ h8) * 8;   // K frag, ks=0
    const int ko1 = l16*64 + ((4 + quad) ^ h8) * 8;   // K frag, ks=1
    const int vo0 = l16*32 + (((quad >> 1))     ^ h4) * 8 + (quad & 1) * 4;   // V keys 4q..4q+3
    const int vo1 = l16*32 + ((2 + (quad >> 1)) ^ h4) * 8 + (quad & 1) * 4;   // V keys 16+4q..+3

    bf16x8 ones;
#pragma unroll
    for (int j = 0; j < 8; ++j) ones[j] = (__bf16)1.0f;

    f32x4 ot[4][4] = {};    // O^T[dh-tile][q-tile]
    f32x4 lsum[4]  = {};

    // DMA issue helper (tile t into buffer base)
    auto issue = [&](int t, u16* kb, u16* vb) {
        __builtin_amdgcn_global_load_lds(
            (__attribute__((address_space(1))) void*)(srcK + (size_t)t*32*DHEAD),
            (__attribute__((address_space(3))) void*)(kb + tid*8), 16, 0, 0);
        __builtin_amdgcn_global_load_lds(
            (__attribute__((address_space(1))) void*)(srcV + t*32),
            (__attribute__((address_space(3))) void*)(vb + tid*8), 16, 0, 0);
    };

    // per-tile compute (r4-proven body)
    auto body = [&](const u16* Kb, const u16* Vb) {
        // V^T frags hoisted early (independent of S; LDS latency hides under QK MFMAs)
        V8 vt[4];
#pragma unroll
        for (int dt = 0; dt < 4; ++dt) {
            vt[dt].h[0] = *(const s16x4*)(const void*)(Vb + dt*512 + vo0);
            vt[dt].h[1] = *(const s16x4*)(const void*)(Vb + dt*512 + vo1);
        }

        // S^T = K * Q^T, sequential over mt to cap live f32 registers
        B8 pb[4];
#pragma unroll
        for (int mt = 0; mt < 2; ++mt) {
            bf16x8 kf0 = *(const bf16x8*)(const void*)(Kb + mt*1024 + ko0);
            bf16x8 kf1 = *(const bf16x8*)(const void*)(Kb + mt*1024 + ko1);
            f32x4 s[4] = {};
            __builtin_amdgcn_s_setprio(1);
#pragma unroll
            for (int nt = 0; nt < 4; ++nt)
                s[nt] = __builtin_amdgcn_mfma_f32_16x16x32_bf16(kf0, qb[nt][0], s[nt], 0, 0, 0);
#pragma unroll
            for (int nt = 0; nt < 4; ++nt)
                s[nt] = __builtin_amdgcn_mfma_f32_16x16x32_bf16(kf1, qb[nt][1], s[nt], 0, 0, 0);
            __builtin_amdgcn_s_setprio(0);
#pragma unroll
            for (int nt = 0; nt < 4; ++nt) {
                float p0 = __builtin_amdgcn_exp2f(s[nt][0]);
                float p1 = __builtin_amdgcn_exp2f(s[nt][1]);
                float p2 = __builtin_amdgcn_exp2f(s[nt][2]);
                float p3 = __builtin_amdgcn_exp2f(s[nt][3]);
                pb[nt].w[2*mt]   = pkbf(p0, p1);
                pb[nt].w[2*mt+1] = pkbf(p2, p3);
            }
        }

        // lsum += ones * P; O^T += V^T * P^T (full-rate 16x16x32, matching slot->key permutation)
        __builtin_amdgcn_s_setprio(1);
#pragma unroll
        for (int nt = 0; nt < 4; ++nt)
            lsum[nt] = __builtin_amdgcn_mfma_f32_16x16x32_bf16(ones, pb[nt].f, lsum[nt], 0, 0, 0);
#pragma unroll
        for (int dt = 0; dt < 4; ++dt)
#pragma unroll
            for (int nt = 0; nt < 4; ++nt)
                ot[dt][nt] = __builtin_amdgcn_mfma_f32_16x16x32_bf16(vt[dt].f, pb[nt].f, ot[dt][nt], 0, 0, 0);
        __builtin_amdgcn_s_setprio(0);
    };

    // rotating buffer pointers: compute on cur, issue into iss (2 tiles ahead)
    u16 *Kc = Ks,        *Vc = Vt;          // current (tile kt)
    u16 *Ki = Ks + 4096, *Vi = Vt + 4096;   // issue target (tile kt+2)

    // prologue: issue tiles 0 and 1
    issue(0, Ks, Vt);
    issue(1, Ks + 2048, Vt + 2048);

    for (int kt = 0; kt < SS/32 - 2; ++kt) {
        // wait: oldest 2 loads (tile kt) done; tile kt+1's stay in flight. Raw barrier.
        asm volatile("s_waitcnt vmcnt(2)\n\ts_barrier" ::: "memory");
        issue(kt + 2, Ki, Vi);
        body(Kc, Vc);
        // rotate: cur += 2048 (wrap 3), issue += 2048 (wrap 3)
        Kc = (Kc == Ks + 4096) ? Ks : Kc + 2048;
        Vc = (Vc == Vt + 4096) ? Vt : Vc + 2048;
        Ki = (Ki == Ks + 4096) ? Ks : Ki + 2048;
        Vi = (Vi == Vt + 4096) ? Vt : Vi + 2048;
    }
    // peeled tile 62: tile 63's loads still outstanding
    asm volatile("s_waitcnt vmcnt(2)\n\ts_barrier" ::: "memory");
    body(Kc, Vc);
    Kc = (Kc == Ks + 4096) ? Ks : Kc + 2048;
    Vc = (Vc == Vt + 4096) ? Vt : Vc + 2048;
    // peeled tile 63: full drain
    asm volatile("s_waitcnt vmcnt(0)\n\ts_barrier" ::: "memory");
    body(Kc, Vc);

    // epilogue: O = O^T / lsum (lsum already complete per lane), packed 8B stores
    float inv[4];
#pragma unroll
    for (int nt = 0; nt < 4; ++nt) inv[nt] = 1.0f / lsum[nt][0];
#pragma unroll
    for (int dt = 0; dt < 4; ++dt)
#pragma unroll
        for (int nt = 0; nt < 4; ++nt) {
            u64 w = (u64)pkbf(ot[dt][nt][0]*inv[nt], ot[dt][nt][1]*inv[nt])
                  | ((u64)pkbf(ot[dt][nt][2]*inv[nt], ot[dt][nt][3]*inv[nt]) << 32);
            *(u64*)(outb + ((size_t)(b*SS + qbase + nt*16 + l16))*D_MODEL
                         + h*64 + dt*16 + quad*4) = w;
        }
}

// ---------------------------------------------------------------- launcher
extern "C" void kernel_launch(void* const* d_in, const int* in_sizes, int n_in,
                              void* d_out, int out_size, void* d_ws, size_t ws_size,
                              hipStream_t stream)
{
    (void)in_sizes; (void)n_in; (void)out_size; (void)ws_size;
    const float* x  = (const float*)d_in[0];
    const float* wq = (const float*)d_in[1];
    const float* wo = (const float*)d_in[2];
    const float* bo = (const float*)d_in[3];

    char* ws = (char*)d_ws;
    u16* xb    = (u16*)(ws);                          // 16 MiB  [8192][1024] bf16 x
    u16* wqb   = (u16*)(ws + (size_t)(16 << 20));     //  2 MiB
    u16* wob   = (u16*)(ws + (size_t)(18 << 20));     //  2 MiB
    u16* qkvb  = (u16*)(ws + (size_t)(20 << 20));     // 16 MiB  [64][2048][64]
    u16* qkvTb = (u16*)(ws + (size_t)(36 << 20));     // 16 MiB  [64][64][2048]
    u16* attb  = xb;                                  // reuse x-bf16 buffer for attention output

    cvt_all_kernel<<<(N4X + 2*N4W) / 256, 256, 0, stream>>>(x, wq, wo, xb, wqb, wob);
    gemm_qkv_kernel<<<(MM/128) * (D_MODEL/128), 256, 0, stream>>>(xb, wqb, qkvb, qkvTb);
    attn_kernel<<<BB * NH * (SS/256), 256, 0, stream>>>(qkvb, qkvTb, attb);
    gemm_out_kernel<<<(MM/128) * (D_MODEL/128), 256, 0, stream>>>(attb, wob, bo, (float*)d_out);
}